// Round 5
// baseline (194.725 us; speedup 1.0000x reference)
//
#include <hip/hip_runtime.h>

#define NC 5
#define VEC 8

typedef float fvec4 __attribute__((ext_vector_type(4)));

__global__ __launch_bounds__(256) void flow_cpab_kernel(
    const float* __restrict__ x, const float* __restrict__ theta,
    const float* __restrict__ B, float* __restrict__ out, int n)
{
    // LDS tables, built per-block by lanes 0..11 (overlapped with x loads)
    __shared__ float4 s_k0[NC];     // {a, b, bosa, isa} per cell
    __shared__ float4 s_q[12];      // {Lb=log|xb+bosa|, sgn, xb, isb} per tix
    __shared__ float4 s_thr[12];    // cumulative crossing-time thresholds
    __shared__ float4 s_pA[60];     // {Ccum, Lcum, x_entry, a_f}
    __shared__ float4 s_pB[60];     // {b_f, bosa_f, 0, 0}

    const int tid = threadIdx.x;
    const float EPS  = 1e-7f;
    const float TINY = 1e-12f;
    const float BIG  = 1e10f;
    const float LOG_TINY = -27.631021115928547f;   // ln(1e-12)

    // ---- issue global loads first so HBM latency overlaps table build ----
    const int base = (blockIdx.x * blockDim.x + tid) * VEC;
    float xs[VEC];
    const bool inb  = (base < n);
    const bool full = inb && (base + VEC <= n);
    if (full) {
        float4 x0 = *(const float4*)(x + base);
        float4 x1 = *(const float4*)(x + base + 4);
        xs[0]=x0.x; xs[1]=x0.y; xs[2]=x0.z; xs[3]=x0.w;
        xs[4]=x1.x; xs[5]=x1.y; xs[6]=x1.z; xs[7]=x1.w;
    } else {
        for (int p = 0; p < VEC; ++p)
            xs[p] = (inb && base + p < n) ? x[base + p] : 0.5f;
    }

    // ---- in-block table build (lanes 0..11 of wave 0) ----
    if (tid < 12) {
        float a[NC], b[NC], bosa[NC], isa[NC], isb[NC];
        #pragma unroll
        for (int c = 0; c < NC; ++c) {
            float av = 0.f, bv = 0.f;
            #pragma unroll
            for (int j = 0; j < 6; ++j) {
                float th = theta[j];
                av = fmaf(B[(2 * c) * 6 + j], th, av);
                bv = fmaf(B[(2 * c + 1) * 6 + j], th, bv);
            }
            const bool  big = fabsf(av) > 1e-8f;
            const float sa  = big ? av : 1.0f;
            const float sb  = (fabsf(bv) > TINY) ? bv : TINY;
            a[c] = av; b[c] = bv;
            bosa[c] = bv / sa; isa[c] = 1.0f / sa; isb[c] = 1.0f / sb;
        }
        if (tid < NC)
            s_k0[tid] = make_float4(a[tid], b[tid], bosa[tid], isa[tid]);

        const int d  = tid / 6;    // 0 = right, 1 = left
        const int jb = tid % 6;    // boundary index

        {   // first-leg aux: start cell c0 for this (dir, boundary)
            const int  c0 = (d == 0) ? jb - 1 : jb;
            const int  cs = (c0 >= 0 && c0 < NC) ? c0 : 0;
            const float xb  = (float)jb / 5.0f;
            const float num = xb + bosa[cs];
            const float Lb  = __logf(fmaxf(fabsf(num), 1e-30f));
            const float sgn = (num >= 0.f) ? 1.f : -1.f;
            s_q[tid] = make_float4(Lb, sgn, xb, isb[cs]);
        }

        // full-cell walk: cumulative thresholds + per-count packages
        float Ccum = 0.f, Lcum = 0.f;
        float th[4] = {BIG, BIG, BIG, BIG};
        for (int m = 0; m < 5; ++m) {
            const int  cf   = (d == 0) ? (jb + m) : (jb - 1 - m);
            const bool sent = (cf < 0) || (cf >= NC);
            const float xe  = (d == 0) ? ((float)cf / 5.0f)
                                       : ((float)(cf + 1) / 5.0f);
            const float af    = sent ? 0.f : a[cf];
            const float bf    = sent ? 0.f : b[cf];
            const float bosaf = sent ? 0.f : bosa[cf];
            s_pA[tid * 5 + m] = make_float4(Ccum, Lcum, xe, af);
            s_pB[tid * 5 + m] = make_float4(bf, bosaf, 0.f, 0.f);

            float T = BIG;
            if (!sent) {
                const float xL  = (float)cf / 5.0f;
                const float xR  = (float)(cf + 1) / 5.0f;
                const float xce = (d == 0) ? xL : xR;
                const float xbt = (d == 0) ? xR : xL;
                const float v   = fmaf(af, xce, bf);
                const bool  big = fabsf(af) > 1e-8f;
                const float den  = xce + bosaf;
                const float sden = (fabsf(den) > TINY) ? den : TINY;
                const float ratio = __fdividef(xbt + bosaf, sden);
                const float ta = __logf(fmaxf(ratio, TINY)) * isa[cf];
                const float tb = (xbt - xce) * isb[cf];
                float thit = big ? ta : tb;
                const bool valid = (fabsf(v) > TINY) && (thit >= 0.f) &&
                                   (!big || (ratio > 0.f));
                T = valid ? thit : BIG;
            }
            const float newC = Ccum + T;
            if (m < 4) th[m] = newC;
            if (T < BIG) Lcum = fmaf(af, T, Lcum);
            Ccum = newC;
        }
        s_thr[tid] = make_float4(th[0], th[1], th[2], th[3]);
    }
    __syncthreads();

    if (!inb) return;

    float zz[VEC], ll[VEC];
    #pragma unroll
    for (int p = 0; p < VEC; ++p) {
        const float xc = fminf(fmaxf(xs[p], EPS), 1.0f - EPS);
        const int c0 = min((int)(xc * (float)NC), NC - 1);

        const float4 k0 = s_k0[c0];
        const float a = k0.x, b = k0.y, bosa = k0.z, isa = k0.w;
        const bool  big = fabsf(a) > 1e-8f;

        // ---- first leg: one log, no division ----
        const float v     = fmaf(a, xc, b);
        const bool  right = (v >= 0.0f);
        const int   tix   = (right ? 0 : 6) + c0 + (right ? 1 : 0);
        const float4 q    = s_q[tix];          // {Lb, sgn, xb, isb}

        const float den  = xc + bosa;
        const float l    = __logf(fmaxf(fabsf(den), TINY));
        const float diff = fmaxf(q.x - l, LOG_TINY);   // log(max(ratio,TINY))
        const float th_a = diff * isa;
        const float th_b = (q.z - xc) * q.w;
        float thit0 = big ? th_a : th_b;
        const bool valid = (fabsf(v) > TINY) && (thit0 >= 0.0f) &&
                           (!big || (den * q.y > 0.0f));
        thit0 = valid ? thit0 : BIG;

        const bool  hit0 = (thit0 < 1.0f);
        const float tr   = 1.0f - thit0;

        // ---- full-cell count via precomputed cumulative thresholds ----
        const float4 th = s_thr[tix];
        const int m = (th.x < tr) + (th.y < tr) + (th.z < tr) + (th.w < tr);
        const int pix = tix * 5 + m;
        const float4 pA = s_pA[pix];
        const float4 pB = s_pB[pix];

        // ---- final partial-cell evolution: one exp ----
        const float xe    = hit0 ? pA.z : xc;
        const float t_f   = hit0 ? (tr - pA.x) : 1.0f;
        const float af    = hit0 ? pA.w : a;
        const float bf    = hit0 ? pB.x : b;
        const float bosaf = hit0 ? pB.y : bosa;
        const float lbase = hit0 ? fmaf(a, thit0, pA.y) : 0.0f;

        const bool  bigf = fabsf(af) > 1e-8f;
        const float eat  = __expf(af * t_f);
        zz[p] = bigf ? fmaf(xe, eat, bosaf * (eat - 1.0f))
                     : fmaf(bf, t_f, xe);
        ll[p] = fmaf(af, t_f, lbase);
    }

    if (full) {
        fvec4 z0 = {zz[0], zz[1], zz[2], zz[3]};
        fvec4 z1 = {zz[4], zz[5], zz[6], zz[7]};
        fvec4 l0 = {ll[0], ll[1], ll[2], ll[3]};
        fvec4 l1 = {ll[4], ll[5], ll[6], ll[7]};
        __builtin_nontemporal_store(z0, (fvec4*)(out + base));
        __builtin_nontemporal_store(z1, (fvec4*)(out + base + 4));
        __builtin_nontemporal_store(l0, (fvec4*)(out + n + base));
        __builtin_nontemporal_store(l1, (fvec4*)(out + n + base + 4));
    } else {
        for (int p = 0; p < VEC; ++p) {
            if (base + p < n) {
                out[base + p]     = zz[p];
                out[n + base + p] = ll[p];
            }
        }
    }
}

extern "C" void kernel_launch(void* const* d_in, const int* in_sizes, int n_in,
                              void* d_out, int out_size, void* d_ws, size_t ws_size,
                              hipStream_t stream) {
    const float* x     = (const float*)d_in[0];
    const float* theta = (const float*)d_in[1];
    const float* B     = (const float*)d_in[2];
    float* out = (float*)d_out;
    const int n = in_sizes[0];

    const int threads = 256;
    const int per_block = threads * VEC;
    const int blocks = (n + per_block - 1) / per_block;
    flow_cpab_kernel<<<blocks, threads, 0, stream>>>(x, theta, B, out, n);
}

// Round 6
// 191.017 us; speedup vs baseline: 1.0194x; 1.0194x over previous
//
#include <hip/hip_runtime.h>

#define NC 5
#define VEC 4

typedef float fvec4 __attribute__((ext_vector_type(4)));

// ws float layout (346 floats):
// [0..47]    row1[tix]  = {bosa, isa, Lb=log|xb+bosa|, num=xb+bosa}   (tix=0..11)
// [48..95]   thr[tix]   = {th0, th1, th2, th3} cumulative crossing times
// [96..335]  pkg[tix*5+m] = {af, bosaf, xe, Lcum}
// [336..345] a[0..4], b[0..4]

__global__ void setup_kernel(const float* __restrict__ theta,
                             const float* __restrict__ B,
                             float* __restrict__ ws)
{
    const int tid = threadIdx.x;
    const float TINY = 1e-12f, BIG = 1e10f;

    float a[NC], b[NC], bosa[NC], isa[NC], isb[NC];
    #pragma unroll
    for (int c = 0; c < NC; ++c) {
        float av = 0.f, bv = 0.f;
        #pragma unroll
        for (int j = 0; j < 6; ++j) {
            float th = theta[j];
            av = fmaf(B[(2 * c) * 6 + j], th, av);
            bv = fmaf(B[(2 * c + 1) * 6 + j], th, bv);
        }
        const bool  big = fabsf(av) > 1e-8f;
        const float sa  = big ? av : 1.0f;
        const float sb  = (fabsf(bv) > TINY) ? bv : TINY;
        a[c] = av; b[c] = bv;
        bosa[c] = bv / sa; isa[c] = 1.0f / sa; isb[c] = 1.0f / sb;
    }

    if (tid < 10) ws[336 + tid] = (tid < 5) ? a[tid] : b[tid - 5];

    if (tid < 12) {
        const int d  = tid / 6;     // 0 = right, 1 = left
        const int jb = tid % 6;     // boundary index
        const int c0r = (d == 0) ? jb - 1 : jb;    // first-leg cell
        const int cs  = min(max(c0r, 0), NC - 1);  // clamped (unused rows)
        const float xb  = (float)jb * 0.2f;
        const float num = xb + bosa[cs];
        const float Lb  = __logf(fmaxf(fabsf(num), 1e-30f));
        ws[tid * 4 + 0] = bosa[cs];
        ws[tid * 4 + 1] = isa[cs];
        ws[tid * 4 + 2] = Lb;
        ws[tid * 4 + 3] = num;

        float Ccum = 0.f, Lcum = 0.f;
        float th[4] = {BIG, BIG, BIG, BIG};
        for (int m = 0; m < 5; ++m) {
            const int  cf   = (d == 0) ? (jb + m) : (jb - 1 - m);
            const bool sent = (cf < 0) || (cf >= NC);
            const float xe  = (d == 0) ? (float)cf * 0.2f
                                       : (float)(cf + 1) * 0.2f;
            const float af    = sent ? 0.f : a[cf];
            const float bosaf = sent ? 0.f : bosa[cf];
            const int pix = tid * 5 + m;
            ws[96 + pix * 4 + 0] = af;
            ws[96 + pix * 4 + 1] = bosaf;
            ws[96 + pix * 4 + 2] = xe;
            ws[96 + pix * 4 + 3] = Lcum;

            float T = BIG;
            if (!sent) {
                const float bf  = b[cf];
                const float xL  = (float)cf * 0.2f;
                const float xR  = (float)(cf + 1) * 0.2f;
                const float xce = (d == 0) ? xL : xR;
                const float xbt = (d == 0) ? xR : xL;
                const float v   = fmaf(af, xce, bf);
                const bool  big = fabsf(af) > 1e-8f;
                const float den  = xce + bosaf;
                const float sden = (fabsf(den) > TINY) ? den : TINY;
                const float ratio = __fdividef(xbt + bosaf, sden);
                const float ta = __logf(fmaxf(ratio, TINY)) * isa[cf];
                const float tb = (xbt - xce) * isb[cf];
                float thit = big ? ta : tb;
                const bool valid = (fabsf(v) > TINY) && (thit >= 0.f) &&
                                   (!big || (ratio > 0.f));
                T = valid ? thit : BIG;
            }
            if (m < 4) th[m] = Ccum + T;
            if (T < BIG) Lcum = fmaf(af, T, Lcum);
            Ccum += T;
        }
        ws[48 + tid * 4 + 0] = th[0];
        ws[48 + tid * 4 + 1] = th[1];
        ws[48 + tid * 4 + 2] = th[2];
        ws[48 + tid * 4 + 3] = th[3];
    }
}

__global__ __launch_bounds__(256) void flow_cpab_kernel(
    const float* __restrict__ x, const float* __restrict__ ws,
    float* __restrict__ out, int n)
{
    __shared__ float4 s[84];   // [0..11] row1, [12..23] thr, [24..83] pkg

    const int tid = threadIdx.x;
    const float EPS  = 1e-7f;
    const float TINY = 1e-12f;
    const float BIG  = 1e10f;
    const float LOG_TINY = -27.631021115928547f;   // ln(1e-12)

    // issue x loads first so HBM latency overlaps LDS fill
    const int base = (blockIdx.x * blockDim.x + tid) * VEC;
    float xs[VEC];
    const bool inb  = (base < n);
    const bool full = inb && (base + VEC <= n);
    if (full) {
        float4 xv = *(const float4*)(x + base);
        xs[0] = xv.x; xs[1] = xv.y; xs[2] = xv.z; xs[3] = xv.w;
    } else {
        for (int p = 0; p < VEC; ++p)
            xs[p] = (inb && base + p < n) ? x[base + p] : 0.5f;
    }

    if (tid < 84) s[tid] = ((const float4*)ws)[tid];

    // wave-uniform cell coefficients (scalar loads)
    const float a0 = ws[336], a1 = ws[337], a2 = ws[338], a3 = ws[339], a4 = ws[340];
    const float b0 = ws[341], b1 = ws[342], b2 = ws[343], b3 = ws[344], b4 = ws[345];

    __syncthreads();

    if (!inb) return;

    float zz[VEC], ll[VEC];
    #pragma unroll
    for (int p = 0; p < VEC; ++p) {
        const float xc = fminf(fmaxf(xs[p], EPS), 1.0f - EPS);
        const int c0 = min((int)(xc * (float)NC), NC - 1);

        // a,b via cndmask select chains (no LDS latency stage)
        const float a = (c0 == 0) ? a0 : (c0 == 1) ? a1 : (c0 == 2) ? a2
                       : (c0 == 3) ? a3 : a4;
        const float b = (c0 == 0) ? b0 : (c0 == 1) ? b1 : (c0 == 2) ? b2
                       : (c0 == 3) ? b3 : b4;

        const float v     = fmaf(a, xc, b);
        const bool  right = (v >= 0.0f);
        const int   jb    = right ? (c0 + 1) : c0;
        const int   tix   = (right ? 0 : 6) + jb;

        const float4 r1 = s[tix];        // {bosa, isa, Lb, num}
        const float4 th = s[12 + tix];   // thresholds

        const float xb   = 0.2f * (float)jb;
        const float den  = xc + r1.x;
        const float l    = __logf(fmaxf(fabsf(den), TINY));
        const float diff = fmaxf(r1.z - l, LOG_TINY);
        const bool  big  = fabsf(a) > 1e-8f;
        const float th_a = diff * r1.y;
        const float sb   = (fabsf(b) > TINY) ? b : TINY;
        const float th_b = (xb - xc) * __builtin_amdgcn_rcpf(sb);
        float thit0 = big ? th_a : th_b;
        const bool valid = (fabsf(v) > TINY) && (thit0 >= 0.0f) &&
                           (!big || (den * r1.w > 0.0f));
        thit0 = valid ? thit0 : BIG;

        const bool  hit0 = (thit0 < 1.0f);
        const float tr   = 1.0f - thit0;

        const int m = (th.x < tr) + (th.y < tr) + (th.z < tr) + (th.w < tr);
        const float Ccum = (m == 0) ? 0.0f : (m == 1) ? th.x
                          : (m == 2) ? th.y : (m == 3) ? th.z : th.w;
        const float4 pk = s[24 + tix * 5 + m];   // {af, bosaf, xe, Lcum}

        const float af    = hit0 ? pk.x : a;
        const float bosaf = hit0 ? pk.y : r1.x;
        const float xe    = hit0 ? pk.z : xc;
        const float lbase = hit0 ? fmaf(a, thit0, pk.w) : 0.0f;
        const float t_f   = hit0 ? (tr - Ccum) : 1.0f;

        const bool  bigf = fabsf(af) > 1e-8f;
        const float bf   = bigf ? af * bosaf : bosaf;   // recover b of final cell
        const float eat  = __expf(af * t_f);
        zz[p] = bigf ? fmaf(xe, eat, bosaf * (eat - 1.0f))
                     : fmaf(bf, t_f, xe);
        ll[p] = fmaf(af, t_f, lbase);
    }

    if (full) {
        fvec4 zv = {zz[0], zz[1], zz[2], zz[3]};
        fvec4 lv = {ll[0], ll[1], ll[2], ll[3]};
        __builtin_nontemporal_store(zv, (fvec4*)(out + base));
        __builtin_nontemporal_store(lv, (fvec4*)(out + n + base));
    } else {
        for (int p = 0; p < VEC; ++p) {
            if (base + p < n) {
                out[base + p]     = zz[p];
                out[n + base + p] = ll[p];
            }
        }
    }
}

extern "C" void kernel_launch(void* const* d_in, const int* in_sizes, int n_in,
                              void* d_out, int out_size, void* d_ws, size_t ws_size,
                              hipStream_t stream) {
    const float* x     = (const float*)d_in[0];
    const float* theta = (const float*)d_in[1];
    const float* B     = (const float*)d_in[2];
    float* out = (float*)d_out;
    float* ws  = (float*)d_ws;
    const int n = in_sizes[0];

    setup_kernel<<<1, 64, 0, stream>>>(theta, B, ws);

    const int threads = 256;
    const int per_block = threads * VEC;
    const int blocks = (n + per_block - 1) / per_block;
    flow_cpab_kernel<<<blocks, threads, 0, stream>>>(x, ws, out, n);
}